// Round 2
// baseline (604.102 us; speedup 1.0000x reference)
//
#include <hip/hip_runtime.h>

#define NB    133
#define NBP   136            // gT n-stride: mult of 8 (16B chunks), 68 words = 4 mod 32 -> 2-way banks
#define BATCH 256
#define HEADS 8
#define CDIM  128
#define DDIM  1024
#define MROWS (BATCH * NB)   // 34048 = 266*128
#define NDIM  (HEADS * CDIM)

typedef __bf16 bf16_t;
typedef bf16_t bf16x8 __attribute__((ext_vector_type(8)));
typedef float  f32x4  __attribute__((ext_vector_type(4)));
typedef unsigned short ushort_t;

__device__ __forceinline__ unsigned short f2bf(float f) {
  unsigned u = __float_as_uint(f);
  u += 0x7fffu + ((u >> 16) & 1u);
  return (unsigned short)(u >> 16);
}
__device__ __forceinline__ void load_lds16(const void* g, void* l) {
  __builtin_amdgcn_global_load_lds(
      (__attribute__((address_space(1))) void*)(g),
      (__attribute__((address_space(3))) void*)(l), 16, 0, 0);
}

// ---------------- fp32 -> bf16 convert (8 elems/thread) ----------------
__global__ __launch_bounds__(256) void cvt_kernel(const float* __restrict__ src,
                                                  unsigned short* __restrict__ dst,
                                                  int n8) {
  int i = blockIdx.x * 256 + threadIdx.x;
  if (i >= n8) return;
  const float4* s4 = (const float4*)src;
  float4 a = s4[(size_t)i * 2];
  float4 b = s4[(size_t)i * 2 + 1];
  union { unsigned short u[8]; uint4 v; } p;
  p.u[0] = f2bf(a.x); p.u[1] = f2bf(a.y); p.u[2] = f2bf(a.z); p.u[3] = f2bf(a.w);
  p.u[4] = f2bf(b.x); p.u[5] = f2bf(b.y); p.u[6] = f2bf(b.z); p.u[7] = f2bf(b.w);
  ((uint4*)dst)[i] = p.v;
}

// ---------------- adjacency bitmasks: rm[i] bits over j, cm[j] bits over i ----------------
__global__ __launch_bounds__(256) void mask_kernel(const float* __restrict__ adj,
                                                   unsigned* __restrict__ rm,
                                                   unsigned* __restrict__ cm) {
  const int tid = threadIdx.x, lane = tid & 63, wv = tid >> 6;
  for (int i = 0; i < NB; ++i) {
    bool on = (tid < NB) && (adj[i * NB + tid] != 0.f);
    unsigned long long bb = __ballot(on);
    if (wv < 3) {
      if (lane == 0)  rm[i * 6 + wv * 2]     = (unsigned)bb;
      if (lane == 32) rm[i * 6 + wv * 2 + 1] = (unsigned)(bb >> 32);
    }
  }
  for (int j = 0; j < NB; ++j) {
    bool on = (tid < NB) && (adj[tid * NB + j] != 0.f);
    unsigned long long bb = __ballot(on);
    if (wv < 3) {
      if (lane == 0)  cm[j * 6 + wv * 2]     = (unsigned)bb;
      if (lane == 32) cm[j * 6 + wv * 2 + 1] = (unsigned)(bb >> 32);
    }
  }
  if (tid < (144 - NB) * 6) rm[NB * 6 + tid] = 0;  // zero rows 133..143
}

// ---------------- GEMM: g = x @ W^T, fused si/sj + transposed gT output ----------------
// A=xb[34048][1024], B=wb[1024][1024] (both K-contig). 128x128 tile, BK=64,
// 16B-chunk XOR swizzle (sub ^ row&7) -> conflict-free ds_read_b128.
__global__ __launch_bounds__(256) void gemm_kernel(const unsigned short* __restrict__ xb,
                                                   const unsigned short* __restrict__ wb,
                                                   const float* __restrict__ attn_w,
                                                   unsigned short* __restrict__ gT,
                                                   float* __restrict__ si_ws,
                                                   float* __restrict__ sj_ws) {
  __shared__ __attribute__((aligned(16))) char smem[33792];  // As+Bs (32KB) then tbuf (4x64x66x2)
  __shared__ float sred[2][4][64];
  unsigned short* As = (unsigned short*)smem;
  unsigned short* Bs = (unsigned short*)(smem + 16384);
  const int tid = threadIdx.x;
  const int h = blockIdx.x & 7, bm = blockIdx.x >> 3;
  const int lane = tid & 63, w = tid >> 6;
  const int wm = (w & 1) * 64, wn = (w >> 1) * 64;
  const int q = lane >> 4, li = lane & 15;

  f32x4 acc[4][4] = {};
  const unsigned short* Ab = xb + (size_t)bm * 128 * DDIM;
  const unsigned short* Bb = wb + (size_t)h * 128 * DDIM;

  for (int kt = 0; kt < 16; ++kt) {
    const int k0 = kt * 64;
#pragma unroll
    for (int s = 0; s < 4; ++s) {
      const int c = tid + s * 256;
      const int row = c >> 3, gsub = (c & 7) ^ (row & 7);
      load_lds16(Ab + (size_t)row * DDIM + k0 + gsub * 8, As + c * 8);
      load_lds16(Bb + (size_t)row * DDIM + k0 + gsub * 8, Bs + c * 8);
    }
    __syncthreads();
#pragma unroll
    for (int kk = 0; kk < 2; ++kk) {
      bf16x8 af[4], bfr[4];
#pragma unroll
      for (int mi = 0; mi < 4; ++mi)
        af[mi] = *(const bf16x8*)(As + (wm + mi * 16 + li) * 64 + (((kk * 4 + q) ^ (li & 7)) * 8));
#pragma unroll
      for (int ni = 0; ni < 4; ++ni)
        bfr[ni] = *(const bf16x8*)(Bs + (wn + ni * 16 + li) * 64 + (((kk * 4 + q) ^ (li & 7)) * 8));
#pragma unroll
      for (int mi = 0; mi < 4; ++mi)
#pragma unroll
        for (int ni = 0; ni < 4; ++ni)
          acc[mi][ni] = __builtin_amdgcn_mfma_f32_16x16x32_bf16(af[mi], bfr[ni], acc[mi][ni], 0, 0, 0);
    }
    __syncthreads();
  }

  // ---- fused si/sj: per-row dot with wr/wl, reduce over 16 col-lanes ----
  float wl[4], wr[4];
#pragma unroll
  for (int ni = 0; ni < 4; ++ni) {
    wl[ni] = attn_w[wn + ni * 16 + li];
    wr[ni] = attn_w[CDIM + wn + ni * 16 + li];
  }
#pragma unroll
  for (int mi = 0; mi < 4; ++mi)
#pragma unroll
    for (int rr = 0; rr < 4; ++rr) {
      float pj = 0.f, pi = 0.f;
#pragma unroll
      for (int ni = 0; ni < 4; ++ni) {
        pj += acc[mi][ni][rr] * wl[ni];
        pi += acc[mi][ni][rr] * wr[ni];
      }
#pragma unroll
      for (int d = 1; d < 16; d <<= 1) {
        pj += __shfl_xor(pj, d);
        pi += __shfl_xor(pi, d);
      }
      if (li == 0) {
        sred[0][w][mi * 16 + q * 4 + rr] = pj;
        sred[1][w][mi * 16 + q * 4 + rr] = pi;
      }
    }
  __syncthreads();
  {
    const int row = tid & 127;
    const int which = tid >> 7;        // 0: sj(wl), 1: si(wr)
    const int wlo = (row >> 6) & 1;    // rows 0-63: waves 0&2; 64-127: waves 1&3
    const float v = sred[which][wlo][row & 63] + sred[which][wlo + 2][row & 63];
    const int rg = bm * 128 + row;
    const int b = rg / NB, n = rg - b * NB;
    float* dst = which ? si_ws : sj_ws;
    dst[(b * HEADS + h) * NB + n] = v;
  }

  // ---- per-wave transpose of the 64x64 sub-tile into LDS, then coalesced gT store ----
  unsigned short* tb = (unsigned short*)smem + w * 64 * 66;  // [col 0..63][row 0..63], stride 66
#pragma unroll
  for (int mi = 0; mi < 4; ++mi)
#pragma unroll
    for (int ni = 0; ni < 4; ++ni)
#pragma unroll
      for (int rp = 0; rp < 2; ++rp) {
        unsigned lo = f2bf(acc[mi][ni][rp * 2]);
        unsigned hi = f2bf(acc[mi][ni][rp * 2 + 1]);
        const int c = ni * 16 + li, r = mi * 16 + q * 4 + rp * 2;
        *(unsigned*)(tb + c * 66 + r) = lo | (hi << 16);
      }
  __syncthreads();
  {
    const int l = lane;
    const int rloc = 2 * (l & 31);
    const int rg = bm * 128 + wm + rloc;
    const int b0 = rg / NB, n0 = rg - b0 * NB;
    const bool cross = (n0 == NB - 1);
    const int b1 = cross ? b0 + 1 : b0, n1 = cross ? 0 : n0 + 1;
    const size_t hb = (size_t)h * 128 + wn;
#pragma unroll 4
    for (int fi = 0; fi < 32; ++fi) {
      const int fl = fi * 2 + (l >> 5);
      const unsigned v = *(const unsigned*)(tb + fl * 66 + rloc);
      const size_t fb = (hb + fl) * 256;
      gT[(fb + b0) * NBP + n0] = (unsigned short)v;
      gT[(fb + b1) * NBP + n1] = (unsigned short)(v >> 16);
    }
  }
}

// ---------------- aggregation + inline column softmax stats ----------------
// Block per (b,h). gT staged straight via global_load_lds (already transposed).
__global__ __launch_bounds__(256) void agg_kernel(const unsigned short* __restrict__ gT,
                                                  const float* __restrict__ si_ws,
                                                  const float* __restrict__ sj_ws,
                                                  const unsigned* __restrict__ rm,
                                                  const unsigned* __restrict__ cm,
                                                  float* __restrict__ out) {
  __shared__ __attribute__((aligned(16))) unsigned short gL[128 * NBP + 32];
  __shared__ float4 smr[160];  // (sj, m, 1/denom, 0) per j
  const int tid = threadIdx.x;
  const int b = blockIdx.x >> 3, h = blockIdx.x & 7;
  const int base = (b * HEADS + h) * NB;

  // 1) async stage: 128 f-rows x 17 chunks (loads stay in flight through stats phase)
  const unsigned short* gsrc = gT + ((size_t)h * 128 * 256 + b) * NBP;
  for (int c = tid; c < 128 * 17; c += 256) {
    const int f = c / 17, ch = c - f * 17;
    load_lds16(gsrc + (size_t)f * 256 * NBP + ch * 8, gL + c * 8);
  }
  if (tid < 16) ((unsigned*)(gL + 128 * NBP))[tid] = 0;  // zero LDS tail pad

  // 2) column stats: thread j computes m_j, 1/denom_j over masked i (si reads are wave-uniform)
  if (tid < 160) {
    float4 v = {0.f, 0.f, 0.f, 0.f};
    if (tid < NB) {
      const int j = tid;
      const float sjv = sj_ws[base + j];
      float m = -3.0e38f;
#pragma unroll
      for (int wd = 0; wd < 5; ++wd) {
        const unsigned bits = cm[j * 6 + wd];
        const int lim = (wd == 4) ? (NB - 128) : 32;
        for (int i2 = 0; i2 < lim; ++i2) {
          float e = si_ws[base + wd * 32 + i2] + sjv;
          e = e > 0.f ? e : 0.2f * e;
          m = ((bits >> i2) & 1u) ? fmaxf(m, e) : m;
        }
      }
      float s = 0.f;
#pragma unroll
      for (int wd = 0; wd < 5; ++wd) {
        const unsigned bits = cm[j * 6 + wd];
        const int lim = (wd == 4) ? (NB - 128) : 32;
        for (int i2 = 0; i2 < lim; ++i2) {
          float e = si_ws[base + wd * 32 + i2] + sjv;
          e = e > 0.f ? e : 0.2f * e;
          s += ((bits >> i2) & 1u) ? __expf(e - m) : 0.f;
        }
      }
      v.x = sjv; v.y = m; v.z = 1.0f / s;
    }
    smr[tid] = v;
  }
  __syncthreads();  // drains staging + stats visible

  // 3) MFMA: A = attention weights (registers), B = gL
  const int lane = tid & 63, wv = tid >> 6, q = lane >> 4, li = lane & 15;
  for (int mt = wv; mt < 9; mt += 4) {
    const int il = mt * 16 + li;
    const float si_r = si_ws[base + (il < NB ? il : NB - 1)];
    const unsigned* rmr = rm + il * 6;
    const unsigned rw0 = rmr[0], rw1 = rmr[1], rw2 = rmr[2], rw3 = rmr[3], rw4 = rmr[4];
    f32x4 acc[8] = {};
#pragma unroll
    for (int ks = 0; ks < 5; ++ks) {
      const int j0 = ks * 32 + q * 8;
      const unsigned wsel = (ks == 0 ? rw0 : ks == 1 ? rw1 : ks == 2 ? rw2 : ks == 3 ? rw3 : rw4);
      const unsigned bits = wsel >> (q * 8);
      union { unsigned short s[8]; bf16x8 v; } af;
#pragma unroll
      for (int jj = 0; jj < 8; ++jj) {
        const float4 sv = smr[j0 + jj];
        float e = si_r + sv.x;
        e = e > 0.f ? e : 0.2f * e;
        const float wgt = ((bits >> jj) & 1u) ? __expf(e - sv.y) * sv.z : 0.f;
        af.s[jj] = f2bf(wgt);
      }
#pragma unroll
      for (int n = 0; n < 8; ++n) {
        const bf16x8 bv = *(const bf16x8*)(gL + (n * 16 + li) * NBP + j0);
        acc[n] = __builtin_amdgcn_mfma_f32_16x16x32_bf16(af.v, bv, acc[n], 0, 0, 0);
      }
    }
#pragma unroll
    for (int n = 0; n < 8; ++n)
#pragma unroll
      for (int rr = 0; rr < 4; ++rr) {
        const int i = mt * 16 + q * 4 + rr;
        if (i < NB)
          out[((size_t)(b * NB + i)) * NDIM + h * CDIM + n * 16 + li] = acc[n][rr];
      }
  }
}

extern "C" void kernel_launch(void* const* d_in, const int* in_sizes, int n_in,
                              void* d_out, int out_size, void* d_ws, size_t ws_size,
                              hipStream_t stream) {
  const float* x      = (const float*)d_in[0];
  const float* W      = (const float*)d_in[1];
  const float* attn_w = (const float*)d_in[2];
  const float* adj    = (const float*)d_in[3];
  float* out = (float*)d_out;
  char* ws = (char*)d_ws;

  // workspace layout (bytes), total ~145.3 MB
  unsigned short* xb = (unsigned short*)(ws + 0);            // 69,730,304
  unsigned short* wb = (unsigned short*)(ws + 69730304);     //  2,097,152
  unsigned short* gT = (unsigned short*)(ws + 71827456);     // 71,303,168  [h][f][b][NBP]
  float* si = (float*)(ws + 143130624);                      //  1,089,536  [b][h][133]
  float* sj = (float*)(ws + 144220160);                      //  1,089,536
  unsigned* rm = (unsigned*)(ws + 145309696);                //      3,456  [144][6]
  unsigned* cm = (unsigned*)(ws + 145313152);                //      3,456

  cvt_kernel<<<(MROWS * DDIM / 8 + 255) / 256, 256, 0, stream>>>(x, xb, MROWS * DDIM / 8);
  cvt_kernel<<<(NDIM * DDIM / 8 + 255) / 256, 256, 0, stream>>>(W, wb, NDIM * DDIM / 8);
  mask_kernel<<<1, 256, 0, stream>>>(adj, rm, cm);
  gemm_kernel<<<266 * 8, 256, 0, stream>>>(xb, wb, attn_w, gT, si, sj);
  agg_kernel<<<BATCH * HEADS, 256, 0, stream>>>(gT, si, sj, rm, cm, out);
}

// Round 3
// 459.658 us; speedup vs baseline: 1.3142x; 1.3142x over previous
//
#include <hip/hip_runtime.h>

#define NB    133
#define NBP   136            // gT f-row stride in shorts: 68 words = 4 mod 32 -> 2-way banks (free)
#define BATCH 256
#define HEADS 8
#define CDIM  128
#define DDIM  1024
#define MROWS (BATCH * NB)   // 34048 = 266*128
#define NDIM  (HEADS * CDIM)
#define BH    (BATCH * HEADS)

typedef __bf16 bf16_t;
typedef bf16_t bf16x8 __attribute__((ext_vector_type(8)));
typedef float  f32x4  __attribute__((ext_vector_type(4)));

__device__ __forceinline__ unsigned short f2bf(float f) {
  unsigned u = __float_as_uint(f);
  u += 0x7fffu + ((u >> 16) & 1u);
  return (unsigned short)(u >> 16);
}
__device__ __forceinline__ void load_lds16(const void* g, void* l) {
  __builtin_amdgcn_global_load_lds(
      (__attribute__((address_space(1))) void*)(g),
      (__attribute__((address_space(3))) void*)(l), 16, 0, 0);
}

// ---------------- fp32 -> bf16 convert, x and W in one launch ----------------
__global__ __launch_bounds__(256) void cvt_kernel(const float* __restrict__ x,
                                                  const float* __restrict__ W,
                                                  unsigned short* __restrict__ xb,
                                                  unsigned short* __restrict__ wb) {
  const int nx = MROWS * DDIM / 8, nw = NDIM * DDIM / 8;
  int i = blockIdx.x * 256 + threadIdx.x;
  const float* src; unsigned short* dst; int k;
  if (i < nx)           { src = x; dst = xb; k = i; }
  else if (i < nx + nw) { src = W; dst = wb; k = i - nx; }
  else return;
  const float4* s4 = (const float4*)src;
  float4 a = s4[(size_t)k * 2];
  float4 b = s4[(size_t)k * 2 + 1];
  union { unsigned short u[8]; uint4 v; } p;
  p.u[0] = f2bf(a.x); p.u[1] = f2bf(a.y); p.u[2] = f2bf(a.z); p.u[3] = f2bf(a.w);
  p.u[4] = f2bf(b.x); p.u[5] = f2bf(b.y); p.u[6] = f2bf(b.z); p.u[7] = f2bf(b.w);
  ((uint4*)dst)[k] = p.v;
}

// ---------------- adjacency bitmasks, one block per row/col ----------------
__global__ __launch_bounds__(192) void mask_kernel(const float* __restrict__ adj,
                                                   unsigned* __restrict__ rm,
                                                   unsigned* __restrict__ cm) {
  const int tid = threadIdx.x, lane = tid & 63, wv = tid >> 6, blk = blockIdx.x;
  if (blk < 144) {
    const int i = blk;
    bool on = (i < NB) && (tid < NB) && (adj[i * NB + tid] != 0.f);
    unsigned long long bb = __ballot(on);
    if (lane == 0)  rm[i * 6 + wv * 2]     = (unsigned)bb;
    if (lane == 32) rm[i * 6 + wv * 2 + 1] = (unsigned)(bb >> 32);
  } else {
    const int j = blk - 144;
    bool on = (tid < NB) && (adj[tid * NB + j] != 0.f);
    unsigned long long bb = __ballot(on);
    if (lane == 0)  cm[j * 6 + wv * 2]     = (unsigned)bb;
    if (lane == 32) cm[j * 6 + wv * 2 + 1] = (unsigned)(bb >> 32);
  }
}

// ---------------- GEMM: g = x @ W^T, fused si/sj (R1 structure + XOR swizzle) ----------------
__global__ __launch_bounds__(256) void gemm_kernel(const unsigned short* __restrict__ xb,
                                                   const unsigned short* __restrict__ wb,
                                                   const float* __restrict__ attn_w,
                                                   unsigned short* __restrict__ gb,
                                                   float* __restrict__ si_ws,
                                                   float* __restrict__ sj_ws) {
  __shared__ __attribute__((aligned(16))) unsigned short As[128 * 32];
  __shared__ __attribute__((aligned(16))) unsigned short Bs[128 * 32];
  __shared__ float sred[2][4][64];
  const int tid = threadIdx.x;
  const int h = blockIdx.x & 7, bm = blockIdx.x >> 3;
  const int lane = tid & 63, w = tid >> 6;
  const int wm = (w & 1) * 64, wn = (w >> 1) * 64;
  const int q = lane >> 4, li = lane & 15;
  const int c0 = tid, c1 = tid + 256;

  f32x4 acc[4][4] = {};
  const unsigned short* Ab = xb + (size_t)bm * 128 * DDIM;
  const unsigned short* Bb = wb + (size_t)h * 128 * DDIM;

  for (int kt = 0; kt < 32; ++kt) {
    const int k0 = kt * 32;
    // slot (row, s) holds global 16B-chunk s ^ ((row>>1)&3): conflict-free frag reads
    load_lds16(Ab + (size_t)(c0 >> 2) * DDIM + k0 + (((c0 & 3) ^ ((c0 >> 3) & 3)) * 8), &As[c0 * 8]);
    load_lds16(Ab + (size_t)(c1 >> 2) * DDIM + k0 + (((c1 & 3) ^ ((c1 >> 3) & 3)) * 8), &As[c1 * 8]);
    load_lds16(Bb + (size_t)(c0 >> 2) * DDIM + k0 + (((c0 & 3) ^ ((c0 >> 3) & 3)) * 8), &Bs[c0 * 8]);
    load_lds16(Bb + (size_t)(c1 >> 2) * DDIM + k0 + (((c1 & 3) ^ ((c1 >> 3) & 3)) * 8), &Bs[c1 * 8]);
    __syncthreads();

    bf16x8 af[4], bfr[4];
    const int sub = (q ^ ((li >> 1) & 3)) * 8;
#pragma unroll
    for (int mi = 0; mi < 4; ++mi)
      af[mi] = *(const bf16x8*)&As[(wm + mi * 16 + li) * 32 + sub];
#pragma unroll
    for (int ni = 0; ni < 4; ++ni)
      bfr[ni] = *(const bf16x8*)&Bs[(wn + ni * 16 + li) * 32 + sub];
#pragma unroll
    for (int mi = 0; mi < 4; ++mi)
#pragma unroll
      for (int ni = 0; ni < 4; ++ni)
        acc[mi][ni] = __builtin_amdgcn_mfma_f32_16x16x32_bf16(af[mi], bfr[ni], acc[mi][ni], 0, 0, 0);
    __syncthreads();
  }

  // fused si/sj: dot rows with wl/wr, reduce over the 16 col-lanes of each quad
  float wl[4], wr[4];
#pragma unroll
  for (int ni = 0; ni < 4; ++ni) {
    wl[ni] = attn_w[wn + ni * 16 + li];
    wr[ni] = attn_w[CDIM + wn + ni * 16 + li];
  }
#pragma unroll
  for (int mi = 0; mi < 4; ++mi)
#pragma unroll
    for (int rr = 0; rr < 4; ++rr) {
      float pj = 0.f, pi = 0.f;
#pragma unroll
      for (int ni = 0; ni < 4; ++ni) {
        pj += acc[mi][ni][rr] * wl[ni];
        pi += acc[mi][ni][rr] * wr[ni];
      }
#pragma unroll
      for (int d = 1; d < 16; d <<= 1) {
        pj += __shfl_xor(pj, d);
        pi += __shfl_xor(pi, d);
      }
      if (li == 0) {
        sred[0][w][mi * 16 + q * 4 + rr] = pj;
        sred[1][w][mi * 16 + q * 4 + rr] = pi;
      }
    }
  __syncthreads();
  {
    const int row = tid & 127;
    const int which = tid >> 7;
    const int wlo = (row >> 6) & 1;
    const float v = sred[which][wlo][row & 63] + sred[which][wlo + 2][row & 63];
    const int rg = bm * 128 + row;
    const int b = rg / NB, n = rg - b * NB;
    float* dst = which ? si_ws : sj_ws;
    dst[(b * HEADS + h) * NB + n] = v;
  }

  // store g in normal layout (R1 epilogue)
#pragma unroll
  for (int mi = 0; mi < 4; ++mi)
#pragma unroll
    for (int ni = 0; ni < 4; ++ni) {
      const int col = h * 128 + wn + ni * 16 + li;
      const size_t row0 = (size_t)(bm * 128 + wm + mi * 16 + q * 4);
#pragma unroll
      for (int rr = 0; rr < 4; ++rr)
        gb[(row0 + rr) * NDIM + col] = f2bf(acc[mi][ni][rr]);
    }
}

// ---------------- column softmax stats: smrg[bh][j] = (sj_j, m_j + ln(denom_j)) ----------------
__global__ __launch_bounds__(192) void stats_kernel(const float* __restrict__ si_ws,
                                                    const float* __restrict__ sj_ws,
                                                    const unsigned* __restrict__ cm,
                                                    float2* __restrict__ smrg) {
  __shared__ float siL[NB];
  const int tid = threadIdx.x;
  const int base = blockIdx.x * NB;
  if (tid < NB) siL[tid] = si_ws[base + tid];
  __syncthreads();
  if (tid >= 160) return;
  float2 o = {0.f, 0.f};
  if (tid < NB) {
    const int j = tid;
    const float sjv = sj_ws[base + j];
    float m = -3.0e38f;
#pragma unroll
    for (int wd = 0; wd < 5; ++wd) {
      unsigned bits = cm[j * 6 + wd];
      while (bits) {
        const int i = __ffs(bits) - 1; bits &= bits - 1;
        float e = siL[wd * 32 + i] + sjv;
        e = e > 0.f ? e : 0.2f * e;
        m = fmaxf(m, e);
      }
    }
    float s = 0.f;
#pragma unroll
    for (int wd = 0; wd < 5; ++wd) {
      unsigned bits = cm[j * 6 + wd];
      while (bits) {
        const int i = __ffs(bits) - 1; bits &= bits - 1;
        float e = siL[wd * 32 + i] + sjv;
        e = e > 0.f ? e : 0.2f * e;
        s += __expf(e - m);
      }
    }
    o.x = sjv;
    o.y = m + __logf(s);   // weight = exp(e - o.y): rd folded into the exponent
  }
  smrg[(size_t)blockIdx.x * 160 + tid] = o;
}

// ---------------- aggregation: block = (b, h, f-half); LDS transpose of g ----------------
__global__ __launch_bounds__(256) void agg_kernel(const unsigned short* __restrict__ gb,
                                                  const float* __restrict__ si_ws,
                                                  const float2* __restrict__ smrg,
                                                  const unsigned* __restrict__ rm,
                                                  float* __restrict__ out) {
  __shared__ __attribute__((aligned(16))) unsigned short gTl[64 * NBP + 32]; // [f][j]
  __shared__ __attribute__((aligned(8))) float2 smrL[160];
  const int tid = threadIdx.x;
  const int bh = blockIdx.x >> 1, fh = blockIdx.x & 1;
  const int b = bh >> 3, h = bh & 7;
  const int base = bh * NB;

  // zero pad: cols 133..135 of every f-row + 32-short tail (MFMA K-overreads hit these)
  if (tid < 64) {
    gTl[tid * NBP + 133] = 0;
    *(unsigned*)&gTl[tid * NBP + 134] = 0;
  }
  if (tid >= 64 && tid < 80) *(unsigned*)&gTl[64 * NBP + 2 * (tid - 64)] = 0;
  if (tid < 160) smrL[tid] = smrg[(size_t)bh * 160 + tid];

  // coalesced read (16 lanes x 8B per j-row) + transpose via b16 LDS writes
  const unsigned short* gsrc = gb + (size_t)(b * NB) * NDIM + h * CDIM + fh * 64;
  for (int u = tid; u < NB * 16; u += 256) {
    const int j = u >> 4, fg = u & 15;
    const uint2 d = *(const uint2*)(gsrc + (size_t)j * NDIM + fg * 4);
    const int f0 = fg * 4;
    gTl[(f0 + 0) * NBP + j] = (unsigned short)(d.x);
    gTl[(f0 + 1) * NBP + j] = (unsigned short)(d.x >> 16);
    gTl[(f0 + 2) * NBP + j] = (unsigned short)(d.y);
    gTl[(f0 + 3) * NBP + j] = (unsigned short)(d.y >> 16);
  }
  __syncthreads();

  const int lane = tid & 63, wv = tid >> 6, q = lane >> 4, li = lane & 15;
  for (int mt = wv; mt < 9; mt += 4) {
    const int il = mt * 16 + li;
    const float si_r = si_ws[base + (il < NB ? il : NB - 1)];
    const unsigned* rmr = rm + il * 6;
    f32x4 acc[4] = {};
#pragma unroll
    for (int ks = 0; ks < 5; ++ks) {
      const int j0 = ks * 32 + q * 8;
      const unsigned bits = rmr[ks] >> (q * 8);
      bf16x8 afv;
#pragma unroll
      for (int jj = 0; jj < 8; ++jj) {
        const float2 sv = smrL[j0 + jj];
        float e = si_r + sv.x;
        e = e > 0.f ? e : 0.2f * e;
        const float wgt = ((bits >> jj) & 1u) ? __expf(e - sv.y) : 0.f;
        afv[jj] = (bf16_t)wgt;
      }
#pragma unroll
      for (int n = 0; n < 4; ++n) {
        const bf16x8 bv = *(const bf16x8*)&gTl[(n * 16 + li) * NBP + j0];
        acc[n] = __builtin_amdgcn_mfma_f32_16x16x32_bf16(afv, bv, acc[n], 0, 0, 0);
      }
    }
    float* obase = out + (size_t)(b * NB) * NDIM + h * CDIM + fh * 64;
#pragma unroll
    for (int n = 0; n < 4; ++n)
#pragma unroll
      for (int rr = 0; rr < 4; ++rr) {
        const int i = mt * 16 + q * 4 + rr;
        if (i < NB) obase[(size_t)i * NDIM + n * 16 + li] = acc[n][rr];
      }
  }
}

extern "C" void kernel_launch(void* const* d_in, const int* in_sizes, int n_in,
                              void* d_out, int out_size, void* d_ws, size_t ws_size,
                              hipStream_t stream) {
  const float* x      = (const float*)d_in[0];
  const float* W      = (const float*)d_in[1];
  const float* attn_w = (const float*)d_in[2];
  const float* adj    = (const float*)d_in[3];
  float* out = (float*)d_out;
  char* ws = (char*)d_ws;

  // workspace layout (bytes), ~143.7 MB; smrg overlays xb (xb dead after gemm)
  unsigned short* xb = (unsigned short*)(ws + 0);            // 69,730,304
  unsigned short* wb = (unsigned short*)(ws + 69730304);     //  2,097,152
  unsigned short* gb = (unsigned short*)(ws + 71827456);     // 69,730,304
  float* si = (float*)(ws + 141557760);                      //  1,089,536
  float* sj = (float*)(ws + 142647296);                      //  1,089,536
  unsigned* rm = (unsigned*)(ws + 143736832);                //      3,456
  unsigned* cm = (unsigned*)(ws + 143740288);                //      3,192
  float2* smrg = (float2*)(ws + 0);                          //  2,621,440 (overlay)

  const int ncvt = (MROWS * DDIM + NDIM * DDIM) / 8;
  cvt_kernel<<<(ncvt + 255) / 256, 256, 0, stream>>>(x, W, xb, wb);
  mask_kernel<<<277, 192, 0, stream>>>(adj, rm, cm);
  gemm_kernel<<<266 * 8, 256, 0, stream>>>(xb, wb, attn_w, gb, si, sj);
  stats_kernel<<<BH, 192, 0, stream>>>(si, sj, cm, smrg);
  agg_kernel<<<BH * 2, 256, 0, stream>>>(gb, si, smrg, rm, out);
}